// Round 4
// baseline (1831.803 us; speedup 1.0000x reference)
//
#include <hip/hip_runtime.h>

// Relation_5841155522972 — talking-heads attention, straight-through hard select.
// out[b,i,h*64+d] = v[b, argmax_j n[b,h,i,j], h*64+d],
// n = LayerNorm_h( softmax_j(QK^T/32) mixed by Wt ).
//
// R4:
//  K1  qkv_gemm       : unchanged fp32 GEMM (qT/kT transposed, V straight).
//  K2a attn_stats_v4  : NO-LDS dots (k via coalesced cached global float2,
//                       q via wave-uniform loads, zero barriers). Bitwise-same
//                       Mm/Ml as R3.
//  K2b attn_select_v4 : no-LDS dots (16i x 64j tile, all 16 h looped), p tile
//                       in LDS (stride 271), 1 barrier, fb-verbatim mix/LN/
//                       argmax, deterministic packed atomicMax merge.
//  K2c gather_v4      : decode key -> gather V rows.
// ws: 52.5 MB (qT/kT/V 48 + Mm/Ml 4 + HiKey 0.5).

#define FMA4(cc, av, bv) \
  cc.x = fmaf(av, bv.x, cc.x); cc.y = fmaf(av, bv.y, cc.y); \
  cc.z = fmaf(av, bv.z, cc.z); cc.w = fmaf(av, bv.w, cc.w);

__global__ __launch_bounds__(256) void qkv_gemm(
    const float* __restrict__ X, const float* __restrict__ Wq,
    const float* __restrict__ Wkv, float* __restrict__ qT,
    float* __restrict__ kT, float* __restrict__ V)
{
  __shared__ __align__(16) float As[16 * 132];
  __shared__ __align__(16) float Bs[16 * 132];
  __shared__ __align__(16) float tb[128 * 32];

  const int t  = threadIdx.x;
  const int bn = blockIdx.x;
  const int bm = blockIdx.y;
  const int m0 = bm * 128, n0 = bn * 128;
  const int ty = t >> 4, tx = t & 15;

  const float* Wbase = (n0 < 1024) ? Wq : Wkv;
  const int nw0 = (n0 < 1024) ? n0 : (n0 - 1024);

  float4 c2[8][2];
#pragma unroll
  for (int a = 0; a < 8; a++) {
    c2[a][0] = make_float4(0.f, 0.f, 0.f, 0.f);
    c2[a][1] = make_float4(0.f, 0.f, 0.f, 0.f);
  }

  const int lr = t >> 1;
  const int lh = t & 1;

  const float4* As4 = (const float4*)As;
  const float4* Bs4 = (const float4*)Bs;

  for (int kb = 0; kb < 64; kb++) {
    const int k0 = kb * 16;
    __syncthreads();
#pragma unroll
    for (int s = 0; s < 2; s++) {
      const int kk = lh * 8 + s * 4;
      float4 av = *(const float4*)&X[(size_t)(m0 + lr) * 1024 + k0 + kk];
      float4 bv = *(const float4*)&Wbase[(size_t)(nw0 + lr) * 1024 + k0 + kk];
      As[(kk + 0) * 132 + lr] = av.x;
      As[(kk + 1) * 132 + lr] = av.y;
      As[(kk + 2) * 132 + lr] = av.z;
      As[(kk + 3) * 132 + lr] = av.w;
      Bs[(kk + 0) * 132 + lr] = bv.x;
      Bs[(kk + 1) * 132 + lr] = bv.y;
      Bs[(kk + 2) * 132 + lr] = bv.z;
      Bs[(kk + 3) * 132 + lr] = bv.w;
    }
    __syncthreads();
#pragma unroll
    for (int kk = 0; kk < 16; kk++) {
      float4 a0 = As4[kk * 33 + ty * 2];
      float4 a1 = As4[kk * 33 + ty * 2 + 1];
      float4 b0 = Bs4[kk * 33 + tx];
      float4 b1 = Bs4[kk * 33 + 16 + tx];
      FMA4(c2[0][0], a0.x, b0); FMA4(c2[0][1], a0.x, b1);
      FMA4(c2[1][0], a0.y, b0); FMA4(c2[1][1], a0.y, b1);
      FMA4(c2[2][0], a0.z, b0); FMA4(c2[2][1], a0.z, b1);
      FMA4(c2[3][0], a0.w, b0); FMA4(c2[3][1], a0.w, b1);
      FMA4(c2[4][0], a1.x, b0); FMA4(c2[4][1], a1.x, b1);
      FMA4(c2[5][0], a1.y, b0); FMA4(c2[5][1], a1.y, b1);
      FMA4(c2[6][0], a1.z, b0); FMA4(c2[6][1], a1.z, b1);
      FMA4(c2[7][0], a1.w, b0); FMA4(c2[7][1], a1.w, b1);
    }
  }

  if (n0 >= 2048) {
    const int nv0 = n0 - 2048;
#pragma unroll
    for (int a = 0; a < 8; a++) {
      *(float4*)&V[(size_t)(m0 + ty * 8 + a) * 1024 + nv0 + tx * 4]      = c2[a][0];
      *(float4*)&V[(size_t)(m0 + ty * 8 + a) * 1024 + nv0 + 64 + tx * 4] = c2[a][1];
    }
    return;
  }

  float* T = (n0 < 1024) ? qT : kT;
  const int nt0 = (n0 < 1024) ? n0 : (n0 - 1024);
  const int bB = m0 >> 10;
  const int i0 = m0 & 1023;
#pragma unroll
  for (int r = 0; r < 4; r++) {
    __syncthreads();
    if ((tx >> 3) == (r & 1)) {
      const int c0 = (tx & 7) * 4;
#pragma unroll
      for (int a = 0; a < 8; a++) {
        const int m = ty * 8 + a;
        float4 val = c2[a][r >> 1];
        tb[m * 32 + ((c0 + 0 + m) & 31)] = val.x;
        tb[m * 32 + ((c0 + 1 + m) & 31)] = val.y;
        tb[m * 32 + ((c0 + 2 + m) & 31)] = val.z;
        tb[m * 32 + ((c0 + 3 + m) & 31)] = val.w;
      }
    }
    __syncthreads();
    const int nl = t >> 3, mq = t & 7;
    float* Trow = T + (size_t)(bB * 1024 + nt0 + (r >> 1) * 64 + (r & 1) * 32 + nl) * 1024 + i0;
#pragma unroll
    for (int l = 0; l < 4; l++) {
      const int mb = (l * 8 + mq) * 4;
      float4 o;
      o.x = tb[(mb + 0) * 32 + ((nl + mb + 0) & 31)];
      o.y = tb[(mb + 1) * 32 + ((nl + mb + 1) & 31)];
      o.z = tb[(mb + 2) * 32 + ((nl + mb + 2) & 31)];
      o.w = tb[(mb + 3) * 32 + ((nl + mb + 3) & 31)];
      *(float4*)(Trow + mb) = o;
    }
  }
}

// ---------------------------------------------------------------------------
// K2a v4: no-LDS stats. grid = b(4) x it(32 x 32i) x js(8 x 128j) = 1024.
// wave = 8i x 128j (2 j/lane). k: coalesced float2 global (L1/L2-served).
// q: wave-uniform loads. Zero barriers. Bitwise-same Mm/Ml as R3.
// ---------------------------------------------------------------------------
__global__ __launch_bounds__(256) void attn_stats_v4(
    const float* __restrict__ qT, const float* __restrict__ kT,
    float* __restrict__ Mm, float* __restrict__ Ml)
{
  const int t  = threadIdx.x;
  const int bx = blockIdx.x;
  const int b  = bx >> 8;
  const int it = (bx >> 3) & 31;
  const int js = bx & 7;
  const int wv = t >> 6;
  const int l  = t & 63;
  const int i0w = __builtin_amdgcn_readfirstlane(it * 32 + wv * 8);
  const int jl = js * 128 + 2 * l;

  const float scale = 0.03125f;

  for (int h = 0; h < 16; h++) {
    const size_t base = (size_t)(b * 1024 + h * 64) * 1024;
    float acc[8][2];
#pragma unroll
    for (int ii = 0; ii < 8; ii++) { acc[ii][0] = 0.f; acc[ii][1] = 0.f; }

#pragma unroll 8
    for (int d = 0; d < 64; d++) {
      const float* qp = qT + base + (size_t)d * 1024 + i0w;
      float4 qa = *(const float4*)qp;
      float4 qb = *(const float4*)(qp + 4);
      float2 kv = *(const float2*)(kT + base + (size_t)d * 1024 + jl);
      acc[0][0] = fmaf(qa.x, kv.x, acc[0][0]); acc[0][1] = fmaf(qa.x, kv.y, acc[0][1]);
      acc[1][0] = fmaf(qa.y, kv.x, acc[1][0]); acc[1][1] = fmaf(qa.y, kv.y, acc[1][1]);
      acc[2][0] = fmaf(qa.z, kv.x, acc[2][0]); acc[2][1] = fmaf(qa.z, kv.y, acc[2][1]);
      acc[3][0] = fmaf(qa.w, kv.x, acc[3][0]); acc[3][1] = fmaf(qa.w, kv.y, acc[3][1]);
      acc[4][0] = fmaf(qb.x, kv.x, acc[4][0]); acc[4][1] = fmaf(qb.x, kv.y, acc[4][1]);
      acc[5][0] = fmaf(qb.y, kv.x, acc[5][0]); acc[5][1] = fmaf(qb.y, kv.y, acc[5][1]);
      acc[6][0] = fmaf(qb.z, kv.x, acc[6][0]); acc[6][1] = fmaf(qb.z, kv.y, acc[6][1]);
      acc[7][0] = fmaf(qb.w, kv.x, acc[7][0]); acc[7][1] = fmaf(qb.w, kv.y, acc[7][1]);
    }

#pragma unroll
    for (int ii = 0; ii < 8; ii++) {
      const float s0 = acc[ii][0] * scale;
      const float s1 = acc[ii][1] * scale;
      float mx = fmaxf(s0, s1);
      mx = fmaxf(mx, __shfl_xor(mx, 1));
      mx = fmaxf(mx, __shfl_xor(mx, 2));
      mx = fmaxf(mx, __shfl_xor(mx, 4));
      mx = fmaxf(mx, __shfl_xor(mx, 8));
      mx = fmaxf(mx, __shfl_xor(mx, 16));
      mx = fmaxf(mx, __shfl_xor(mx, 32));
      float ss = __expf(s0 - mx) + __expf(s1 - mx);
      ss += __shfl_xor(ss, 1);
      ss += __shfl_xor(ss, 2);
      ss += __shfl_xor(ss, 4);
      ss += __shfl_xor(ss, 8);
      ss += __shfl_xor(ss, 16);
      ss += __shfl_xor(ss, 32);
      if (l == ii) {
        const int idx = (((b * 16 + h) * 1024 + i0w + ii) << 3) + js;
        Mm[idx] = mx;
        Ml[idx] = ss;
      }
    }
  }
}

// packed key: monotone(float) << 32 | (1023 - j); atomicMax == (>, tie: min j)
__device__ inline unsigned long long mkkey(float v, int j) {
  unsigned u = __float_as_uint(v);
  u = (u & 0x80000000u) ? ~u : (u | 0x80000000u);
  return ((unsigned long long)u << 32) | (unsigned)(1023 - j);
}

// ---------------------------------------------------------------------------
// K2b v4: grid = b(4) x it(64 x 16i) x js(16 x 64j) = 4096 blocks.
// Dot phase: wave = 4i x 64j (1 j/lane), no-LDS dots, p -> LDS tile.
// Mix phase: fb-verbatim mix/LN/argmax (j = g*16+jj), packed atomicMax.
// ---------------------------------------------------------------------------
__global__ __launch_bounds__(256) void attn_select_v4(
    const float* __restrict__ qT, const float* __restrict__ kT,
    const float* __restrict__ Mm, const float* __restrict__ Ml,
    const float* __restrict__ Wt, const float* __restrict__ ln_g,
    const float* __restrict__ ln_b, unsigned long long* __restrict__ HiKey)
{
  __shared__ __align__(16) float smem[64 * 271 + 512];
  float* ptile = smem;                 // j*271 + i_local*17 + h
  float* mred  = smem + 64 * 271;      // [h*16 + i_local]
  float* rred  = mred + 256;

  const int t  = threadIdx.x;
  const int bx = blockIdx.x;
  const int b  = bx >> 10;
  const int it = (bx >> 4) & 63;
  const int js = bx & 15;
  const int i0 = it << 4;
  const int j0 = js << 6;

  const float scale = 0.03125f;

  // prologue: merge-8 slice stats (fb verbatim; t == h*16 + i_local)
  {
    const int base = (((b * 16 + (t >> 4)) * 1024 + i0 + (t & 15)) << 3);
    const float4 ma = *(const float4*)&Mm[base];
    const float4 mb = *(const float4*)&Mm[base + 4];
    const float4 la = *(const float4*)&Ml[base];
    const float4 lb = *(const float4*)&Ml[base + 4];
    float M = fmaxf(fmaxf(fmaxf(ma.x, ma.y), fmaxf(ma.z, ma.w)),
                    fmaxf(fmaxf(mb.x, mb.y), fmaxf(mb.z, mb.w)));
    float L = la.x * __expf(ma.x - M) + la.y * __expf(ma.y - M) +
              la.z * __expf(ma.z - M) + la.w * __expf(ma.w - M) +
              lb.x * __expf(mb.x - M) + lb.y * __expf(mb.y - M) +
              lb.z * __expf(mb.z - M) + lb.w * __expf(mb.w - M);
    mred[t] = M;
    rred[t] = 1.0f / L;
  }
  __syncthreads();

  // ---- dot phase: wave = 4 i x 64 j ----
  const int wv = t >> 6;
  const int l  = t & 63;
  const int i0w = __builtin_amdgcn_readfirstlane(i0 + wv * 4);
  const int iLw = wv * 4;

  for (int h = 0; h < 16; h++) {
    const size_t base = (size_t)(b * 1024 + h * 64) * 1024;
    float acc[4];
    acc[0] = 0.f; acc[1] = 0.f; acc[2] = 0.f; acc[3] = 0.f;
#pragma unroll 8
    for (int d = 0; d < 64; d++) {
      const float4 qa = *(const float4*)(qT + base + (size_t)d * 1024 + i0w);
      const float kv = kT[base + (size_t)d * 1024 + j0 + l];
      acc[0] = fmaf(qa.x, kv, acc[0]);
      acc[1] = fmaf(qa.y, kv, acc[1]);
      acc[2] = fmaf(qa.z, kv, acc[2]);
      acc[3] = fmaf(qa.w, kv, acc[3]);
    }
#pragma unroll
    for (int ii = 0; ii < 4; ii++) {
      const int iL = iLw + ii;
      const float p = __expf(acc[ii] * scale - mred[h * 16 + iL]) * rred[h * 16 + iL];
      ptile[l * 271 + iL * 17 + h] = p;
    }
  }
  __syncthreads();

  // ---- mix phase (fb verbatim, 16 j per g-thread) ----
  const int i2 = t >> 4;
  const int g  = (t >> 2) & 3;
  const int hq = t & 3;

  float wtr[4][16], gr[4], br[4];
#pragma unroll
  for (int a = 0; a < 4; a++) {
#pragma unroll
    for (int h2 = 0; h2 < 16; h2++) wtr[a][h2] = Wt[(hq * 4 + a) * 16 + h2];
    gr[a] = ln_g[hq * 4 + a];
    br[a] = ln_b[hq * 4 + a];
  }
  float bv[4]; int bix[4];
#pragma unroll
  for (int a = 0; a < 4; a++) { bv[a] = -1e30f; bix[a] = 0; }

#pragma unroll
  for (int jj = 0; jj < 16; jj++) {
    const int j = g * 16 + jj;
    float pv[16];
#pragma unroll
    for (int h2 = 0; h2 < 16; h2++) pv[h2] = ptile[j * 271 + i2 * 17 + h2];
    float mix[4];
#pragma unroll
    for (int a = 0; a < 4; a++) {
      float s0 = 0.f;
#pragma unroll
      for (int h2 = 0; h2 < 16; h2++) s0 = fmaf(pv[h2], wtr[a][h2], s0);
      mix[a] = s0;
    }
    float s1 = mix[0] + mix[1] + mix[2] + mix[3];
    s1 += __shfl_xor(s1, 1);
    s1 += __shfl_xor(s1, 2);
    const float mu = s1 * 0.0625f;
    float s2 = 0.f;
#pragma unroll
    for (int a = 0; a < 4; a++) { const float dd = mix[a] - mu; s2 = fmaf(dd, dd, s2); }
    s2 += __shfl_xor(s2, 1);
    s2 += __shfl_xor(s2, 2);
    const float rstd = rsqrtf(s2 * 0.0625f + 1e-5f);
    const int jg = j0 + j;
#pragma unroll
    for (int a = 0; a < 4; a++) {
      const float nv = (mix[a] - mu) * rstd * gr[a] + br[a];
      if (nv > bv[a]) { bv[a] = nv; bix[a] = jg; }
    }
  }

  // merge over the 4 g-lanes (ties -> smaller j), then one atomic per (a,i)
#pragma unroll
  for (int a = 0; a < 4; a++) {
    float v = bv[a]; int ix = bix[a];
    {
      const float ov = __shfl_xor(v, 4);
      const int oi = __shfl_xor(ix, 4);
      if (ov > v || (ov == v && oi < ix)) { v = ov; ix = oi; }
    }
    {
      const float ov = __shfl_xor(v, 8);
      const int oi = __shfl_xor(ix, 8);
      if (ov > v || (ov == v && oi < ix)) { v = ov; ix = oi; }
    }
    bv[a] = v; bix[a] = ix;
  }

  if (g == 0) {
#pragma unroll
    for (int a = 0; a < 4; a++) {
      const int cell = (b * 16 + hq * 4 + a) * 1024 + i0 + i2;
      atomicMax(&HiKey[cell], mkkey(bv[a], bix[a]));
    }
  }
}

// ---------------------------------------------------------------------------
// K2c v4: decode key -> gather V rows.
// ---------------------------------------------------------------------------
__global__ __launch_bounds__(256) void gather_v4(
    const unsigned long long* __restrict__ HiKey, const float* __restrict__ V,
    float* __restrict__ out)
{
  const int t  = threadIdx.x;
  const int bx = blockIdx.x;
  const int b  = bx >> 6;
  const int it = bx & 63;
  const int i2 = t >> 4;
  const int h  = t & 15;

  const unsigned long long key = HiKey[(b * 16 + h) * 1024 + it * 16 + i2];
  const int j = 1023 - (int)(unsigned)(key & 0xFFFFFFFFull);

  const float* vs = V + (size_t)(b * 1024 + j) * 1024 + h * 64;
  float* dst = out + (size_t)(b * 1024 + it * 16 + i2) * 1024 + h * 64;
#pragma unroll
  for (int w = 0; w < 16; w++)
    *(float4*)(dst + w * 4) = *(const float4*)(vs + w * 4);
}

extern "C" void kernel_launch(void* const* d_in, const int* in_sizes, int n_in,
                              void* d_out, int out_size, void* d_ws, size_t ws_size,
                              hipStream_t stream) {
  const float* x   = (const float*)d_in[0];
  const float* Wq  = (const float*)d_in[1];
  const float* Wkv = (const float*)d_in[2];
  const float* Wt  = (const float*)d_in[3];
  const float* lng = (const float*)d_in[4];
  const float* lnb = (const float*)d_in[5];
  float* out = (float*)d_out;
  float* ws  = (float*)d_ws;                          // 52.5 MB used
  float* qT = ws;                                     // 4M f
  float* kT = ws + (size_t)4 * 1024 * 1024;           // 4M f
  float* V  = ws + (size_t)8 * 1024 * 1024;           // 4M f
  float* Mm = ws + (size_t)12 * 1024 * 1024;          // 512K f
  float* Ml = Mm + 524288;                            // 512K f
  unsigned long long* HiKey =
      (unsigned long long*)(ws + (size_t)13 * 1024 * 1024);  // 64K x 8B

  hipLaunchKernelGGL(qkv_gemm, dim3(24, 32), dim3(256), 0, stream,
                     x, Wq, Wkv, qT, kT, V);
  hipMemsetAsync(HiKey, 0, (size_t)65536 * 8, stream);
  hipLaunchKernelGGL(attn_stats_v4, dim3(1024), dim3(256), 0, stream,
                     qT, kT, Mm, Ml);
  hipLaunchKernelGGL(attn_select_v4, dim3(4096), dim3(256), 0, stream,
                     qT, kT, Mm, Ml, Wt, lng, lnb, HiKey);
  hipLaunchKernelGGL(gather_v4, dim3(256), dim3(256), 0, stream,
                     HiKey, V, out);
}

// Round 5
// 963.500 us; speedup vs baseline: 1.9012x; 1.9012x over previous
//
#include <hip/hip_runtime.h>

// Relation_5841155522972 — talking-heads attention, straight-through hard select.
// out[b,i,h*64+d] = v[b, argmax_j n[b,h,i,j], h*64+d],
// n = LayerNorm_h( softmax_j(QK^T/32) mixed by Wt ).
//
// R5: dot phases rebuilt for VMEM-instruction economy (R4 lesson: 2 VMEM per
// 4 FMA was latency/issue-bound at 11% VALU). Now q float4 x k float4 ->
// 2 VMEM per 16 FMA, register tile 4i x 4j per lane.
//  K1  qkv_gemm       : unchanged fp32 GEMM (qT/kT transposed, V straight).
//  K2a attn_stats_v5  : no-LDS, zero-barrier; wave = 8i x 128j, acc[4][4].
//  K2b attn_select_v5 : dot 16i x 64j per wave (4 h rounds), p -> rotated
//                       ptile (bank-safe), fb-verbatim mix/LN/argmax,
//                       packed atomicMax merge (R4-verified).
//  K2c gather_v4      : decode key -> gather V rows (R4-verified).
// ws: 52.5 MB.

#define FMA4(cc, av, bv) \
  cc.x = fmaf(av, bv.x, cc.x); cc.y = fmaf(av, bv.y, cc.y); \
  cc.z = fmaf(av, bv.z, cc.z); cc.w = fmaf(av, bv.w, cc.w);

__global__ __launch_bounds__(256) void qkv_gemm(
    const float* __restrict__ X, const float* __restrict__ Wq,
    const float* __restrict__ Wkv, float* __restrict__ qT,
    float* __restrict__ kT, float* __restrict__ V)
{
  __shared__ __align__(16) float As[16 * 132];
  __shared__ __align__(16) float Bs[16 * 132];
  __shared__ __align__(16) float tb[128 * 32];

  const int t  = threadIdx.x;
  const int bn = blockIdx.x;
  const int bm = blockIdx.y;
  const int m0 = bm * 128, n0 = bn * 128;
  const int ty = t >> 4, tx = t & 15;

  const float* Wbase = (n0 < 1024) ? Wq : Wkv;
  const int nw0 = (n0 < 1024) ? n0 : (n0 - 1024);

  float4 c2[8][2];
#pragma unroll
  for (int a = 0; a < 8; a++) {
    c2[a][0] = make_float4(0.f, 0.f, 0.f, 0.f);
    c2[a][1] = make_float4(0.f, 0.f, 0.f, 0.f);
  }

  const int lr = t >> 1;
  const int lh = t & 1;

  const float4* As4 = (const float4*)As;
  const float4* Bs4 = (const float4*)Bs;

  for (int kb = 0; kb < 64; kb++) {
    const int k0 = kb * 16;
    __syncthreads();
#pragma unroll
    for (int s = 0; s < 2; s++) {
      const int kk = lh * 8 + s * 4;
      float4 av = *(const float4*)&X[(size_t)(m0 + lr) * 1024 + k0 + kk];
      float4 bv = *(const float4*)&Wbase[(size_t)(nw0 + lr) * 1024 + k0 + kk];
      As[(kk + 0) * 132 + lr] = av.x;
      As[(kk + 1) * 132 + lr] = av.y;
      As[(kk + 2) * 132 + lr] = av.z;
      As[(kk + 3) * 132 + lr] = av.w;
      Bs[(kk + 0) * 132 + lr] = bv.x;
      Bs[(kk + 1) * 132 + lr] = bv.y;
      Bs[(kk + 2) * 132 + lr] = bv.z;
      Bs[(kk + 3) * 132 + lr] = bv.w;
    }
    __syncthreads();
#pragma unroll
    for (int kk = 0; kk < 16; kk++) {
      float4 a0 = As4[kk * 33 + ty * 2];
      float4 a1 = As4[kk * 33 + ty * 2 + 1];
      float4 b0 = Bs4[kk * 33 + tx];
      float4 b1 = Bs4[kk * 33 + 16 + tx];
      FMA4(c2[0][0], a0.x, b0); FMA4(c2[0][1], a0.x, b1);
      FMA4(c2[1][0], a0.y, b0); FMA4(c2[1][1], a0.y, b1);
      FMA4(c2[2][0], a0.z, b0); FMA4(c2[2][1], a0.z, b1);
      FMA4(c2[3][0], a0.w, b0); FMA4(c2[3][1], a0.w, b1);
      FMA4(c2[4][0], a1.x, b0); FMA4(c2[4][1], a1.x, b1);
      FMA4(c2[5][0], a1.y, b0); FMA4(c2[5][1], a1.y, b1);
      FMA4(c2[6][0], a1.z, b0); FMA4(c2[6][1], a1.z, b1);
      FMA4(c2[7][0], a1.w, b0); FMA4(c2[7][1], a1.w, b1);
    }
  }

  if (n0 >= 2048) {
    const int nv0 = n0 - 2048;
#pragma unroll
    for (int a = 0; a < 8; a++) {
      *(float4*)&V[(size_t)(m0 + ty * 8 + a) * 1024 + nv0 + tx * 4]      = c2[a][0];
      *(float4*)&V[(size_t)(m0 + ty * 8 + a) * 1024 + nv0 + 64 + tx * 4] = c2[a][1];
    }
    return;
  }

  float* T = (n0 < 1024) ? qT : kT;
  const int nt0 = (n0 < 1024) ? n0 : (n0 - 1024);
  const int bB = m0 >> 10;
  const int i0 = m0 & 1023;
#pragma unroll
  for (int r = 0; r < 4; r++) {
    __syncthreads();
    if ((tx >> 3) == (r & 1)) {
      const int c0 = (tx & 7) * 4;
#pragma unroll
      for (int a = 0; a < 8; a++) {
        const int m = ty * 8 + a;
        float4 val = c2[a][r >> 1];
        tb[m * 32 + ((c0 + 0 + m) & 31)] = val.x;
        tb[m * 32 + ((c0 + 1 + m) & 31)] = val.y;
        tb[m * 32 + ((c0 + 2 + m) & 31)] = val.z;
        tb[m * 32 + ((c0 + 3 + m) & 31)] = val.w;
      }
    }
    __syncthreads();
    const int nl = t >> 3, mq = t & 7;
    float* Trow = T + (size_t)(bB * 1024 + nt0 + (r >> 1) * 64 + (r & 1) * 32 + nl) * 1024 + i0;
#pragma unroll
    for (int l = 0; l < 4; l++) {
      const int mb = (l * 8 + mq) * 4;
      float4 o;
      o.x = tb[(mb + 0) * 32 + ((nl + mb + 0) & 31)];
      o.y = tb[(mb + 1) * 32 + ((nl + mb + 1) & 31)];
      o.z = tb[(mb + 2) * 32 + ((nl + mb + 2) & 31)];
      o.w = tb[(mb + 3) * 32 + ((nl + mb + 3) & 31)];
      *(float4*)(Trow + mb) = o;
    }
  }
}

// ---------------------------------------------------------------------------
// K2a v5: no-LDS stats, float4 x float4 register tile.
// grid = b(4) x it(32 x 32i) x js(8 x 128j) = 1024. wave = 8i x 128j:
// lane: ih = l>>5 (i-quad), jg = l&31 (j-quad). acc[4][4]. Zero barriers.
// Reduction: lane-local over 4 j, then xor 1,2,4,8,16 within 32-lane half.
// ---------------------------------------------------------------------------
__global__ __launch_bounds__(256) void attn_stats_v5(
    const float* __restrict__ qT, const float* __restrict__ kT,
    float* __restrict__ Mm, float* __restrict__ Ml)
{
  const int t  = threadIdx.x;
  const int bx = blockIdx.x;
  const int b  = bx >> 8;
  const int it = (bx >> 3) & 31;
  const int js = bx & 7;
  const int wv = t >> 6;
  const int l  = t & 63;
  const int ih = l >> 5;
  const int jg = l & 31;
  const int i0w = __builtin_amdgcn_readfirstlane(it * 32 + wv * 8);
  const int iq = i0w + ih * 4;
  const int jq = js * 128 + jg * 4;

  const float scale = 0.03125f;

  for (int h = 0; h < 16; h++) {
    const size_t base = (size_t)(b * 1024 + h * 64) * 1024;
    float4 acc[4];
#pragma unroll
    for (int ii = 0; ii < 4; ii++) acc[ii] = make_float4(0.f, 0.f, 0.f, 0.f);

#pragma unroll 4
    for (int d = 0; d < 64; d++) {
      const float4 qv = *(const float4*)(qT + base + (size_t)d * 1024 + iq);
      const float4 kv = *(const float4*)(kT + base + (size_t)d * 1024 + jq);
      FMA4(acc[0], qv.x, kv);
      FMA4(acc[1], qv.y, kv);
      FMA4(acc[2], qv.z, kv);
      FMA4(acc[3], qv.w, kv);
    }

#pragma unroll
    for (int ii = 0; ii < 4; ii++) {
      const float s0 = acc[ii].x * scale;
      const float s1 = acc[ii].y * scale;
      const float s2 = acc[ii].z * scale;
      const float s3 = acc[ii].w * scale;
      float mx = fmaxf(fmaxf(s0, s1), fmaxf(s2, s3));
      mx = fmaxf(mx, __shfl_xor(mx, 1));
      mx = fmaxf(mx, __shfl_xor(mx, 2));
      mx = fmaxf(mx, __shfl_xor(mx, 4));
      mx = fmaxf(mx, __shfl_xor(mx, 8));
      mx = fmaxf(mx, __shfl_xor(mx, 16));
      float ss = __expf(s0 - mx) + __expf(s1 - mx) +
                 __expf(s2 - mx) + __expf(s3 - mx);
      ss += __shfl_xor(ss, 1);
      ss += __shfl_xor(ss, 2);
      ss += __shfl_xor(ss, 4);
      ss += __shfl_xor(ss, 8);
      ss += __shfl_xor(ss, 16);
      if (jg == ii) {
        const int idx = (((b * 16 + h) * 1024 + iq + ii) << 3) + js;
        Mm[idx] = mx;
        Ml[idx] = ss;
      }
    }
  }
}

// packed key: monotone(float) << 32 | (1023 - j); atomicMax == (>, tie: min j)
__device__ inline unsigned long long mkkey(float v, int j) {
  unsigned u = __float_as_uint(v);
  u = (u & 0x80000000u) ? ~u : (u | 0x80000000u);
  return ((unsigned long long)u << 32) | (unsigned)(1023 - j);
}

// ---------------------------------------------------------------------------
// K2b v5: grid = b(4) x it(64 x 16i) x js(16 x 64j) = 4096 blocks.
// Dot: wave covers 16i x 64j for h = wv*4+hl (4 rounds); lane = 4i x 4j,
// q float4 x k float4 (2 VMEM / 16 FMA). p -> ptile[j*271 + i*17 + hrot],
// hrot = (h + (j>>2)) & 15 (write-bank spread). Mix: fb-verbatim with
// rotated pv read; packed atomicMax merge.
// ---------------------------------------------------------------------------
__global__ __launch_bounds__(256) void attn_select_v5(
    const float* __restrict__ qT, const float* __restrict__ kT,
    const float* __restrict__ Mm, const float* __restrict__ Ml,
    const float* __restrict__ Wt, const float* __restrict__ ln_g,
    const float* __restrict__ ln_b, unsigned long long* __restrict__ HiKey)
{
  __shared__ __align__(16) float smem[64 * 271 + 512];
  float* ptile = smem;                 // j*271 + i_local*17 + hrot
  float* mred  = smem + 64 * 271;      // [h*16 + i_local]
  float* rred  = mred + 256;

  const int t  = threadIdx.x;
  const int bx = blockIdx.x;
  const int b  = bx >> 10;
  const int it = (bx >> 4) & 63;
  const int js = bx & 15;
  const int i0 = it << 4;
  const int j0 = js << 6;

  const float scale = 0.03125f;

  // prologue: merge-8 slice stats (R3/R4-verified; t == h*16 + i_local)
  {
    const int base = (((b * 16 + (t >> 4)) * 1024 + i0 + (t & 15)) << 3);
    const float4 ma = *(const float4*)&Mm[base];
    const float4 mb = *(const float4*)&Mm[base + 4];
    const float4 la = *(const float4*)&Ml[base];
    const float4 lb = *(const float4*)&Ml[base + 4];
    float M = fmaxf(fmaxf(fmaxf(ma.x, ma.y), fmaxf(ma.z, ma.w)),
                    fmaxf(fmaxf(mb.x, mb.y), fmaxf(mb.z, mb.w)));
    float L = la.x * __expf(ma.x - M) + la.y * __expf(ma.y - M) +
              la.z * __expf(ma.z - M) + la.w * __expf(ma.w - M) +
              lb.x * __expf(mb.x - M) + lb.y * __expf(mb.y - M) +
              lb.z * __expf(mb.z - M) + lb.w * __expf(mb.w - M);
    mred[t] = M;
    rred[t] = 1.0f / L;
  }
  __syncthreads();

  // ---- dot phase: lane = (ig: 4 i) x (jq: 4 j); wave h-rounds ----
  const int wv = t >> 6;
  const int l  = t & 63;
  const int jq = l & 15;
  const int ig = l >> 4;
  const int iq = i0 + ig * 4;
  const int jcol = j0 + jq * 4;

#pragma unroll
  for (int hl = 0; hl < 4; hl++) {
    const int h = wv * 4 + hl;
    const size_t base = (size_t)(b * 1024 + h * 64) * 1024;
    float4 acc[4];
#pragma unroll
    for (int ii = 0; ii < 4; ii++) acc[ii] = make_float4(0.f, 0.f, 0.f, 0.f);

#pragma unroll 4
    for (int d = 0; d < 64; d++) {
      const float4 qv = *(const float4*)(qT + base + (size_t)d * 1024 + iq);
      const float4 kv = *(const float4*)(kT + base + (size_t)d * 1024 + jcol);
      FMA4(acc[0], qv.x, kv);
      FMA4(acc[1], qv.y, kv);
      FMA4(acc[2], qv.z, kv);
      FMA4(acc[3], qv.w, kv);
    }

    const int hrot = (h + jq) & 15;   // j>>2 == jq for this lane's 4 j
#pragma unroll
    for (int ii = 0; ii < 4; ii++) {
      const int iL = ig * 4 + ii;
      const float m = mred[h * 16 + iL];
      const float r = rred[h * 16 + iL];
      const float a4[4] = {acc[ii].x, acc[ii].y, acc[ii].z, acc[ii].w};
#pragma unroll
      for (int jj = 0; jj < 4; jj++) {
        const int j = jq * 4 + jj;
        const float p = __expf(a4[jj] * scale - m) * r;
        ptile[j * 271 + iL * 17 + hrot] = p;
      }
    }
  }
  __syncthreads();

  // ---- mix phase (fb verbatim; pv read uses the h rotation) ----
  const int i2 = t >> 4;
  const int g  = (t >> 2) & 3;
  const int hq = t & 3;

  float wtr[4][16], gr[4], br[4];
#pragma unroll
  for (int a = 0; a < 4; a++) {
#pragma unroll
    for (int h2 = 0; h2 < 16; h2++) wtr[a][h2] = Wt[(hq * 4 + a) * 16 + h2];
    gr[a] = ln_g[hq * 4 + a];
    br[a] = ln_b[hq * 4 + a];
  }
  float bv[4]; int bix[4];
#pragma unroll
  for (int a = 0; a < 4; a++) { bv[a] = -1e30f; bix[a] = 0; }

#pragma unroll
  for (int jj = 0; jj < 16; jj++) {
    const int j = g * 16 + jj;
    const int jr = j >> 2;
    float pv[16];
#pragma unroll
    for (int h2 = 0; h2 < 16; h2++)
      pv[h2] = ptile[j * 271 + i2 * 17 + ((h2 + jr) & 15)];
    float mix[4];
#pragma unroll
    for (int a = 0; a < 4; a++) {
      float s0 = 0.f;
#pragma unroll
      for (int h2 = 0; h2 < 16; h2++) s0 = fmaf(pv[h2], wtr[a][h2], s0);
      mix[a] = s0;
    }
    float s1 = mix[0] + mix[1] + mix[2] + mix[3];
    s1 += __shfl_xor(s1, 1);
    s1 += __shfl_xor(s1, 2);
    const float mu = s1 * 0.0625f;
    float s2 = 0.f;
#pragma unroll
    for (int a = 0; a < 4; a++) { const float dd = mix[a] - mu; s2 = fmaf(dd, dd, s2); }
    s2 += __shfl_xor(s2, 1);
    s2 += __shfl_xor(s2, 2);
    const float rstd = rsqrtf(s2 * 0.0625f + 1e-5f);
    const int jg2 = j0 + j;
#pragma unroll
    for (int a = 0; a < 4; a++) {
      const float nv = (mix[a] - mu) * rstd * gr[a] + br[a];
      if (nv > bv[a]) { bv[a] = nv; bix[a] = jg2; }
    }
  }

  // merge over the 4 g-lanes (ties -> smaller j), then one atomic per (a,i)
#pragma unroll
  for (int a = 0; a < 4; a++) {
    float v = bv[a]; int ix = bix[a];
    {
      const float ov = __shfl_xor(v, 4);
      const int oi = __shfl_xor(ix, 4);
      if (ov > v || (ov == v && oi < ix)) { v = ov; ix = oi; }
    }
    {
      const float ov = __shfl_xor(v, 8);
      const int oi = __shfl_xor(ix, 8);
      if (ov > v || (ov == v && oi < ix)) { v = ov; ix = oi; }
    }
    bv[a] = v; bix[a] = ix;
  }

  if (g == 0) {
#pragma unroll
    for (int a = 0; a < 4; a++) {
      const int cell = (b * 16 + hq * 4 + a) * 1024 + i0 + i2;
      atomicMax(&HiKey[cell], mkkey(bv[a], bix[a]));
    }
  }
}

// ---------------------------------------------------------------------------
// K2c: decode key -> gather V rows (R4-verified).
// ---------------------------------------------------------------------------
__global__ __launch_bounds__(256) void gather_v4(
    const unsigned long long* __restrict__ HiKey, const float* __restrict__ V,
    float* __restrict__ out)
{
  const int t  = threadIdx.x;
  const int bx = blockIdx.x;
  const int b  = bx >> 6;
  const int it = bx & 63;
  const int i2 = t >> 4;
  const int h  = t & 15;

  const unsigned long long key = HiKey[(b * 16 + h) * 1024 + it * 16 + i2];
  const int j = 1023 - (int)(unsigned)(key & 0xFFFFFFFFull);

  const float* vs = V + (size_t)(b * 1024 + j) * 1024 + h * 64;
  float* dst = out + (size_t)(b * 1024 + it * 16 + i2) * 1024 + h * 64;
#pragma unroll
  for (int w = 0; w < 16; w++)
    *(float4*)(dst + w * 4) = *(const float4*)(vs + w * 4);
}

extern "C" void kernel_launch(void* const* d_in, const int* in_sizes, int n_in,
                              void* d_out, int out_size, void* d_ws, size_t ws_size,
                              hipStream_t stream) {
  const float* x   = (const float*)d_in[0];
  const float* Wq  = (const float*)d_in[1];
  const float* Wkv = (const float*)d_in[2];
  const float* Wt  = (const float*)d_in[3];
  const float* lng = (const float*)d_in[4];
  const float* lnb = (const float*)d_in[5];
  float* out = (float*)d_out;
  float* ws  = (float*)d_ws;                          // 52.5 MB used
  float* qT = ws;                                     // 4M f
  float* kT = ws + (size_t)4 * 1024 * 1024;           // 4M f
  float* V  = ws + (size_t)8 * 1024 * 1024;           // 4M f
  float* Mm = ws + (size_t)12 * 1024 * 1024;          // 512K f
  float* Ml = Mm + 524288;                            // 512K f
  unsigned long long* HiKey =
      (unsigned long long*)(ws + (size_t)13 * 1024 * 1024);  // 64K x 8B

  hipLaunchKernelGGL(qkv_gemm, dim3(24, 32), dim3(256), 0, stream,
                     x, Wq, Wkv, qT, kT, V);
  hipMemsetAsync(HiKey, 0, (size_t)65536 * 8, stream);
  hipLaunchKernelGGL(attn_stats_v5, dim3(1024), dim3(256), 0, stream,
                     qT, kT, Mm, Ml);
  hipLaunchKernelGGL(attn_select_v5, dim3(4096), dim3(256), 0, stream,
                     qT, kT, Mm, Ml, Wt, lng, lnb, HiKey);
  hipLaunchKernelGGL(gather_v4, dim3(256), dim3(256), 0, stream,
                     HiKey, V, out);
}